// Round 2
// baseline (757.294 us; speedup 1.0000x reference)
//
#include <hip/hip_runtime.h>
#include <stdint.h>

// InnerMonologue: PR = hid @ W_to + b_to ; proj = PR @ W_from + b_from
// out = mask ? proj : hid ; mask = parity of cumulative thought-token count (row 0).
// Outputs concat: PR (B,S,P) | out (B,S,H) | is_private (B,S) | usage (B), all fp32.

#define H 2048
#define P 256
#define BB 4
#define S 8192
#define M_TOTAL (BB * S)

typedef __bf16 bf16x8 __attribute__((ext_vector_type(8)));
typedef float f32x4 __attribute__((ext_vector_type(4)));

__device__ __forceinline__ ushort f2b(float f) {
  // fp32 -> bf16 round-to-nearest-even
  uint32_t u = __float_as_uint(f);
  u += 0x7fffu + ((u >> 16) & 1u);
  return (ushort)(u >> 16);
}

// ---------------- mask / is_private / usage ----------------
__global__ void mask_kernel(const int* __restrict__ tok, const int* __restrict__ tt_p,
                            float* __restrict__ maskf, float* __restrict__ out2,
                            float* __restrict__ out3) {
  __shared__ int segpar[256];
  __shared__ int segcnt[256];
  __shared__ int totalsh;
  const int t = threadIdx.x;
  const int tt = tt_p[0];
  const int base = t * 32;
  unsigned bits = 0;
  for (int i = 0; i < 32; i++) bits |= (unsigned)(tok[base + i] == tt) << i;
  segpar[t] = __popc(bits) & 1;
  __syncthreads();
  int pre = 0;
  for (int j = 0; j < t; j++) pre ^= segpar[j];
  int cnt = 0;
  for (int i = 0; i < 32; i++) {
    int inc = __popc(bits & (0xFFFFFFFFu >> (31 - i))) & 1;  // inclusive parity
    int bit = pre ^ inc;
    cnt += bit;
    float fb = (float)bit;
    maskf[base + i] = fb;
    out2[0 * S + base + i] = fb;
    out2[1 * S + base + i] = fb;
    out2[2 * S + base + i] = fb;
    out2[3 * S + base + i] = fb;
  }
  segcnt[t] = cnt;
  __syncthreads();
  if (t == 0) {
    int tot = 0;
    for (int j = 0; j < 256; j++) tot += segcnt[j];
    totalsh = tot;
  }
  __syncthreads();
  if (t < BB) out3[t] = (float)totalsh / (float)S;
}

// ---------------- weight transpose + fp32->bf16 ----------------
// in: R x C fp32 row-major ; out: C x R bf16 row-major
__global__ void transpose_cvt(const float* __restrict__ in, ushort* __restrict__ out,
                              int R, int C) {
  __shared__ float tile[32][33];
  const int c0 = blockIdx.x * 32, r0 = blockIdx.y * 32;
  const int tx = threadIdx.x, ty = threadIdx.y;  // 32 x 8
#pragma unroll
  for (int j = 0; j < 32; j += 8)
    tile[ty + j][tx] = in[(size_t)(r0 + ty + j) * C + c0 + tx];
  __syncthreads();
#pragma unroll
  for (int j = 0; j < 32; j += 8)
    out[(size_t)(c0 + ty + j) * R + r0 + tx] = f2b(tile[tx][ty + j]);
}

// ---------------- fused: GEMM1 -> LDS -> GEMM2 -> blend ----------------
// grid 256 x 512 threads. 128-row tile per block.
// LDS: sPR 128x264 bf16 (67.5KB) + scratch 33792 bf16 (67.5KB) = 135KB -> 1 block/CU, 8 waves.
__global__ __launch_bounds__(512) void fused_main(
    const float* __restrict__ hid,
    const ushort* __restrict__ wtT,   // P x H bf16  (W_to^T)
    const ushort* __restrict__ wfT,   // H x P bf16  (W_from^T)
    const float* __restrict__ b_to,
    const float* __restrict__ b_from,
    const float* __restrict__ maskf,
    float* __restrict__ out0,         // (B*S, P) fp32
    float* __restrict__ out1)         // (B*S, H) fp32
{
  __shared__ ushort sPR[128 * 264];
  __shared__ ushort scratch[33792];
  ushort* sA = scratch;               // 128 x 72 (phase A)
  ushort* sW = scratch + 128 * 72;    // 256 x 72 (phase A)
  ushort* sWf = scratch;              // 128 x 264 (phase B)

  const int tid = threadIdx.x;
  const int lane = tid & 63, wid = tid >> 6;
  const int quad = lane >> 4, l16 = lane & 15;
  const int row0 = blockIdx.x * 128;

  // ---- Phase A: PR(128x256) = hid_tile(128x2048) @ W_to ----
  const int wrA = wid >> 2;  // 0..1 : 64 rows
  const int wcA = wid & 3;   // 0..3 : 64 cols
  f32x4 acc[4][4];
  const f32x4 zero = {0.f, 0.f, 0.f, 0.f};
#pragma unroll
  for (int i = 0; i < 4; i++)
#pragma unroll
    for (int j = 0; j < 4; j++) acc[i][j] = zero;

  for (int k0 = 0; k0 < H; k0 += 64) {
    // stage A: 128 rows x 64 k, fp32 -> bf16
#pragma unroll
    for (int p = 0; p < 4; p++) {
      int u = p * 512 + tid;          // 2048 float4 units
      int r = u >> 4, cc = u & 15;
      const float4 v = *(const float4*)(hid + (size_t)(row0 + r) * H + k0 + cc * 4);
      ushort4 b;
      b.x = f2b(v.x); b.y = f2b(v.y); b.z = f2b(v.z); b.w = f2b(v.w);
      *(ushort4*)(sA + r * 72 + cc * 4) = b;
    }
    // stage W_to^T: 256 n-rows x 64 k (bf16, direct copy)
#pragma unroll
    for (int p = 0; p < 4; p++) {
      int u = p * 512 + tid;          // 2048 x 16B units
      int n = u >> 3, s = u & 7;
      *(int4*)(sW + n * 72 + s * 8) = *(const int4*)(wtT + (size_t)n * H + k0 + s * 8);
    }
    __syncthreads();
#pragma unroll
    for (int kk = 0; kk < 64; kk += 32) {
      bf16x8 af[4], bfr[4];
#pragma unroll
      for (int t = 0; t < 4; t++)
        af[t] = *(const bf16x8*)(sA + (wrA * 64 + t * 16 + l16) * 72 + kk + quad * 8);
#pragma unroll
      for (int t = 0; t < 4; t++)
        bfr[t] = *(const bf16x8*)(sW + (wcA * 64 + t * 16 + l16) * 72 + kk + quad * 8);
#pragma unroll
      for (int i = 0; i < 4; i++)
#pragma unroll
        for (int j = 0; j < 4; j++)
          acc[i][j] = __builtin_amdgcn_mfma_f32_16x16x32_bf16(af[i], bfr[j], acc[i][j], 0, 0, 0);
    }
    __syncthreads();
  }

  // epilogue A: +b_to, write PR fp32 to out0, bf16 copy into sPR
#pragma unroll
  for (int i = 0; i < 4; i++) {
#pragma unroll
    for (int j = 0; j < 4; j++) {
      int col = wcA * 64 + j * 16 + l16;
      float bias = b_to[col];
#pragma unroll
      for (int e = 0; e < 4; e++) {
        int row = wrA * 64 + i * 16 + quad * 4 + e;
        float v = acc[i][j][e] + bias;
        out0[(size_t)(row0 + row) * P + col] = v;
        sPR[row * 264 + col] = f2b(v);
      }
    }
  }

  // ---- Phase B: out(128x2048) = blend(PR @ W_from + b_from) ----
  const int wrB = wid >> 1;  // 0..3 : 32 rows
  const int wcB = wid & 1;   // 0..1 : 64 cols (within 128-col chunk)

  for (int nc = 0; nc < H; nc += 128) {
    // stage W_from^T chunk: 128 n-rows x 256 k  => 4096 int4 units
#pragma unroll
    for (int p = 0; p < 8; p++) {
      int u = p * 512 + tid;
      int n = u >> 5, s = u & 31;
      *(int4*)(sWf + n * 264 + s * 8) = *(const int4*)(wfT + (size_t)(nc + n) * P + s * 8);
    }
    __syncthreads();
    f32x4 acc2[2][4];
#pragma unroll
    for (int i = 0; i < 2; i++)
#pragma unroll
      for (int j = 0; j < 4; j++) acc2[i][j] = zero;
#pragma unroll
    for (int kk = 0; kk < P; kk += 32) {
      bf16x8 af[2], bfr[4];
#pragma unroll
      for (int t = 0; t < 2; t++)
        af[t] = *(const bf16x8*)(sPR + (wrB * 32 + t * 16 + l16) * 264 + kk + quad * 8);
#pragma unroll
      for (int t = 0; t < 4; t++)
        bfr[t] = *(const bf16x8*)(sWf + (wcB * 64 + t * 16 + l16) * 264 + kk + quad * 8);
#pragma unroll
      for (int i = 0; i < 2; i++)
#pragma unroll
        for (int j = 0; j < 4; j++)
          acc2[i][j] = __builtin_amdgcn_mfma_f32_16x16x32_bf16(af[i], bfr[j], acc2[i][j], 0, 0, 0);
    }
    __syncthreads();  // protect sWf before next chunk's staging

    // epilogue chunk: +b_from, blend with hid (row-granular mask), store
#pragma unroll
    for (int i = 0; i < 2; i++) {
#pragma unroll
      for (int e = 0; e < 4; e++) {
        int row = wrB * 32 + i * 16 + quad * 4 + e;
        size_t gr = (size_t)(row0 + row);
        float m = maskf[gr & (S - 1)];
#pragma unroll
        for (int j = 0; j < 4; j++) {
          int col = nc + wcB * 64 + j * 16 + l16;
          float v = acc2[i][j][e] + b_from[col];
          float o = (m != 0.0f) ? v : hid[gr * H + col];
          out1[gr * H + col] = o;
        }
      }
    }
  }
}

extern "C" void kernel_launch(void* const* d_in, const int* in_sizes, int n_in,
                              void* d_out, int out_size, void* d_ws, size_t ws_size,
                              hipStream_t stream) {
  const float* hid    = (const float*)d_in[0];
  const float* W_to   = (const float*)d_in[1];
  const float* b_to   = (const float*)d_in[2];
  const float* W_from = (const float*)d_in[3];
  const float* b_from = (const float*)d_in[4];
  const int*   tok    = (const int*)d_in[5];
  const int*   tt     = (const int*)d_in[6];

  // workspace: W_to^T bf16 (P*H) | W_from^T bf16 (H*P) | mask float (S)  ~2.1MB
  ushort* wtT = (ushort*)d_ws;
  ushort* wfT = wtT + (size_t)P * H;
  float* maskf = (float*)(wfT + (size_t)H * P);

  float* out0 = (float*)d_out;                    // private_reasoning (B,S,P)
  float* out1 = out0 + (size_t)BB * S * P;        // output (B,S,H)
  float* out2 = out1 + (size_t)BB * S * H;        // is_private (B,S)
  float* out3 = out2 + (size_t)BB * S;            // subspace_usage (B)

  hipLaunchKernelGGL(mask_kernel, dim3(1), dim3(256), 0, stream, tok, tt, maskf, out2, out3);
  hipLaunchKernelGGL(transpose_cvt, dim3(P / 32, H / 32), dim3(32, 8), 0, stream, W_to, wtT, H, P);
  hipLaunchKernelGGL(transpose_cvt, dim3(H / 32, P / 32), dim3(32, 8), 0, stream, W_from, wfT, P, H);
  hipLaunchKernelGGL(fused_main, dim3(M_TOTAL / 128), dim3(512), 0, stream,
                     hid, wtT, wfT, b_to, b_from, maskf, out0, out1);
}